// Round 2
// baseline (211.129 us; speedup 1.0000x reference)
//
#include <hip/hip_runtime.h>
#include <math.h>

namespace {

constexpr int kB    = 16384;
constexpr int kS0   = 7;
constexpr int kS1   = 7;
constexpr int kD    = 30;
constexpr int kCells = kB * kS0 * kS1;   // 802816
constexpr int TPB   = 128;               // 128 cells/block -> 15.36 KB LDS -> ~10 blocks/CU
constexpr int NBLK  = kCells / TPB;      // 6272 (exact)
constexpr int F4PB  = TPB * kD / 4;      // 960 float4 per block
constexpr int CHUNKS = F4PB / 64;        // 15 wave-chunks of 64 x 16B
constexpr float kInv7 = 1.0f / 7.0f;
constexpr float kWC = 5.0f;
constexpr float kWN = 0.5f;

__device__ __forceinline__ float sigm(float x) {
    return 1.0f / (1.0f + __expf(-x));
}

__global__ void zero_out(float* out) {
    if (threadIdx.x == 0) out[0] = 0.0f;
}

__global__ void __launch_bounds__(TPB) yolo_loss_kernel(
    const float* __restrict__ pred,
    const int*   __restrict__ grid,
    const float* __restrict__ tbox,
    const int*   __restrict__ tcls,
    float* __restrict__ out)
{
    __shared__ float sp[TPB * kD];        // 15360 B staging for pred tile
    __shared__ float wsum[TPB / 64];

    const int tid   = threadIdx.x;
    const int cell0 = blockIdx.x * TPB;
    const int wave  = tid >> 6;
    const int lane  = tid & 63;

    // --- stage pred tile into LDS via async global->LDS, 8 issues in flight.
    // Wave chunk = 64 lanes x 16B, contiguous in BOTH global and LDS -> matches
    // the wave-uniform-base + lane*16 semantics of global_load_lds.
    // chunk = k*2 + wave; chunks 0..14 valid (15 = 960 float4 / 64), so the
    // bounds check is wave-uniform (only k=7,wave=1 drops out).
    {
        const float4* __restrict__ g4 =
            reinterpret_cast<const float4*>(pred + (size_t)cell0 * kD);
        float4* s4 = reinterpret_cast<float4*>(sp);
        #pragma unroll
        for (int k = 0; k < 8; ++k) {
            const int chunk = k * 2 + wave;
            if (chunk < CHUNKS) {
                const int i = chunk * 64 + lane;   // float4 index
                __builtin_amdgcn_global_load_lds(
                    (const __attribute__((address_space(1))) unsigned int*)(g4 + i),
                    (__attribute__((address_space(3))) unsigned int*)(s4 + i),
                    16, 0, 0);
            }
        }
    }
    __syncthreads();   // drains vmcnt

    const int cell = cell0 + tid;
    const int cj = cell % kS1;            // column -> xg
    const int ci = (cell / kS1) % kS0;    // row    -> yg

    // --- per-cell 30 floats from LDS (float2, tid*30 even -> 8B aligned) ---
    float f[kD];
    {
        const float2* p2 = reinterpret_cast<const float2*>(sp + tid * kD);
        #pragma unroll
        for (int q = 0; q < kD / 2; ++q) {
            float2 t = p2[q];
            f[2 * q]     = t.x;
            f[2 * q + 1] = t.y;
        }
    }

    const float4 tb4 = reinterpret_cast<const float4*>(tbox)[cell];
    const float tox = tb4.x, toy = tb4.y, tw = tb4.z, th = tb4.w;
    const int g  = grid[cell];
    const int tc = tcls[cell];

    const float conf0 = sigm(f[0]);
    const float conf1 = sigm(f[1]);
    float pbx[2], pby[2], pbw[2], pbh[2];
    #pragma unroll
    for (int k = 0; k < 2; ++k) {
        pbx[k] = sigm(f[2 + 4 * k + 0]);
        pby[k] = sigm(f[2 + 4 * k + 1]);
        pbw[k] = sigm(f[2 + 4 * k + 2]);
        pbh[k] = sigm(f[2 + 4 * k + 3]);
    }

    // --- softmax over 20 classes; only the value at tc is needed ---
    float cmax = f[10];
    #pragma unroll
    for (int q = 11; q < 30; ++q) cmax = fmaxf(cmax, f[q]);
    float csum = 0.0f, et = 0.0f;
    #pragma unroll
    for (int q = 0; q < 20; ++q) {
        const float e = __expf(f[10 + q] - cmax);
        csum += e;
        et = (q == tc) ? e : et;     // constant q -> cndmask
    }
    const float cls_t = et / csum;

    // --- IOU of both predicted boxes vs target box ---
    const float x = (float)cj, y = (float)ci;
    const float tcx = (x + tox) * kInv7;   // / S0
    const float tcy = (y + toy) * kInv7;   // / S1
    const float thw = tw * 0.5f, thh = th * 0.5f;
    const float tarea = tw * th;

    float iou0, iou1;
    {
        const float pcx = (x + pbx[0]) * kInv7;
        const float pcy = (y + pby[0]) * kInv7;
        const float pw = pbw[0], ph = pbh[0];
        const float tb_ = fminf(tcx + thw, pcx + pw * 0.5f) - fmaxf(tcx - thw, pcx - pw * 0.5f);
        const float lr_ = fminf(tcy + thh, pcy + ph * 0.5f) - fmaxf(tcy - thh, pcy - ph * 0.5f);
        float inter = tb_ * lr_;
        inter = (tb_ < 0.0f || lr_ < 0.0f) ? 0.0f : inter;
        iou0 = inter / (tarea + pw * ph - inter);
    }
    {
        const float pcx = (x + pbx[1]) * kInv7;
        const float pcy = (y + pby[1]) * kInv7;
        const float pw = pbw[1], ph = pbh[1];
        const float tb_ = fminf(tcx + thw, pcx + pw * 0.5f) - fmaxf(tcx - thw, pcx - pw * 0.5f);
        const float lr_ = fminf(tcy + thh, pcy + ph * 0.5f) - fmaxf(tcy - thh, pcy - ph * 0.5f);
        float inter = tb_ * lr_;
        inter = (tb_ < 0.0f || lr_ < 0.0f) ? 0.0f : inter;
        iou1 = inter / (tarea + pw * ph - inter);
    }

    // argmax (first-max semantics: tie -> box 0)
    const bool b1 = (iou1 > iou0);
    const float bx = b1 ? pbx[1] : pbx[0];
    const float by = b1 ? pby[1] : pby[0];
    const float bw = b1 ? pbw[1] : pbw[0];
    const float bh = b1 ? pbh[1] : pbh[0];
    const float conf_b = b1 ? conf1 : conf0;
    const float iou_b  = b1 ? iou1  : iou0;

    const float dx = bx - tox;
    const float dy = by - toy;
    const float dw = sqrtf(bw) - sqrtf(tw);
    const float dh = sqrtf(bh) - sqrtf(th);
    const float coord = dx * dx + dy * dy + dw * dw + dh * dh;
    const float d1 = conf_b - iou_b;
    const float d2 = 1.0f - cls_t;
    const float obj   = kWC * coord + d1 * d1 + d2 * d2;
    const float noobj = kWN * (conf0 * conf0 + conf1 * conf1);

    float v = (g == 1) ? obj : noobj;

    // --- wave64 shuffle reduce, cross-wave via LDS, one atomic/block ---
    #pragma unroll
    for (int off = 32; off > 0; off >>= 1) v += __shfl_down(v, off, 64);
    if (lane == 0) wsum[wave] = v;
    __syncthreads();
    if (tid == 0) {
        atomicAdd(out, (wsum[0] + wsum[1]) * (1.0f / kB));
    }
}

} // namespace

extern "C" void kernel_launch(void* const* d_in, const int* in_sizes, int n_in,
                              void* d_out, int out_size, void* d_ws, size_t ws_size,
                              hipStream_t stream) {
    const float* pred = (const float*)d_in[0];
    const int*   grid = (const int*)d_in[1];
    const float* tbox = (const float*)d_in[2];
    const int*   tcls = (const int*)d_in[3];
    float* out = (float*)d_out;

    // d_out is re-poisoned (0xAA) before every timed replay -> zero it ourselves.
    zero_out<<<1, 64, 0, stream>>>(out);
    yolo_loss_kernel<<<NBLK, TPB, 0, stream>>>(pred, grid, tbox, tcls, out);
}

// Round 3
// 168.973 us; speedup vs baseline: 1.2495x; 1.2495x over previous
//
#include <hip/hip_runtime.h>
#include <math.h>

namespace {

constexpr int kB    = 16384;
constexpr int kS0   = 7;
constexpr int kS1   = 7;
constexpr int kD    = 30;
constexpr int kCells = kB * kS0 * kS1;   // 802816
constexpr int TPB   = 256;
constexpr int NBLK  = kCells / TPB;      // 3136 (exact)
constexpr int F4PB  = TPB * kD / 4;      // 1920 float4 per block
constexpr float kInv7 = 1.0f / 7.0f;
constexpr float kWC = 5.0f;
constexpr float kWN = 0.5f;

__device__ __forceinline__ float sigm(float x) {
    return 1.0f / (1.0f + __expf(-x));
}

__global__ void zero_out(float* out) {
    if (threadIdx.x == 0) out[0] = 0.0f;
}

__global__ void __launch_bounds__(TPB) yolo_loss_kernel(
    const float* __restrict__ pred,
    const int*   __restrict__ grid,
    const float* __restrict__ tbox,
    const int*   __restrict__ tcls,
    float* __restrict__ out)
{
    __shared__ float sp[TPB * kD];        // 30720 B staging for pred tile
    __shared__ float wsum[TPB / 64];

    const int tid   = threadIdx.x;
    const int cell0 = blockIdx.x * TPB;
    const int cell  = cell0 + tid;
    const int wave  = tid >> 6;
    const int lane  = tid & 63;

    // --- stage pred tile: 1920 float4. Register-staged with STATIC indices so
    // all loads issue before any ds_write (MLP ~10 instead of the rolled
    // loop's MLP=1, which was the round-1 latency wall).
    // 1920 = 256*7 + 128; the 8th load is wave-uniform predicated (waves 0,1).
    const float4* __restrict__ g4 =
        reinterpret_cast<const float4*>(pred + (size_t)cell0 * kD);
    float4* s4 = reinterpret_cast<float4*>(sp);

    float4 r[7];
    #pragma unroll
    for (int k = 0; k < 7; ++k) r[k] = g4[tid + 256 * k];
    float4 r7;
    const bool extra = (tid < F4PB - 256 * 7);      // tid < 128 -> waves 0,1
    if (extra) r7 = g4[256 * 7 + tid];

    // issue the small per-cell loads in the same flight window
    const float4 tb4 = reinterpret_cast<const float4*>(tbox)[cell];
    const int g  = grid[cell];
    const int tc = tcls[cell];

    #pragma unroll
    for (int k = 0; k < 7; ++k) s4[tid + 256 * k] = r[k];
    if (extra) s4[256 * 7 + tid] = r7;
    __syncthreads();

    const int cj = cell % kS1;            // column -> xg
    const int ci = (cell / kS1) % kS0;    // row    -> yg

    // --- per-cell 30 floats from LDS (float2, tid*30 even -> 8B aligned) ---
    float f[kD];
    {
        const float2* p2 = reinterpret_cast<const float2*>(sp + tid * kD);
        #pragma unroll
        for (int q = 0; q < kD / 2; ++q) {
            float2 t = p2[q];
            f[2 * q]     = t.x;
            f[2 * q + 1] = t.y;
        }
    }

    const float tox = tb4.x, toy = tb4.y, tw = tb4.z, th = tb4.w;

    const float conf0 = sigm(f[0]);
    const float conf1 = sigm(f[1]);
    float pbx[2], pby[2], pbw[2], pbh[2];
    #pragma unroll
    for (int k = 0; k < 2; ++k) {
        pbx[k] = sigm(f[2 + 4 * k + 0]);
        pby[k] = sigm(f[2 + 4 * k + 1]);
        pbw[k] = sigm(f[2 + 4 * k + 2]);
        pbh[k] = sigm(f[2 + 4 * k + 3]);
    }

    // --- softmax over 20 classes; only the value at tc is needed ---
    float cmax = f[10];
    #pragma unroll
    for (int q = 11; q < 30; ++q) cmax = fmaxf(cmax, f[q]);
    float csum = 0.0f, et = 0.0f;
    #pragma unroll
    for (int q = 0; q < 20; ++q) {
        const float e = __expf(f[10 + q] - cmax);
        csum += e;
        et = (q == tc) ? e : et;     // constant q -> cndmask
    }
    const float cls_t = et / csum;

    // --- IOU of both predicted boxes vs target box ---
    const float x = (float)cj, y = (float)ci;
    const float tcx = (x + tox) * kInv7;   // / S0
    const float tcy = (y + toy) * kInv7;   // / S1
    const float thw = tw * 0.5f, thh = th * 0.5f;
    const float tarea = tw * th;

    float iou0, iou1;
    {
        const float pcx = (x + pbx[0]) * kInv7;
        const float pcy = (y + pby[0]) * kInv7;
        const float pw = pbw[0], ph = pbh[0];
        const float tb_ = fminf(tcx + thw, pcx + pw * 0.5f) - fmaxf(tcx - thw, pcx - pw * 0.5f);
        const float lr_ = fminf(tcy + thh, pcy + ph * 0.5f) - fmaxf(tcy - thh, pcy - ph * 0.5f);
        float inter = tb_ * lr_;
        inter = (tb_ < 0.0f || lr_ < 0.0f) ? 0.0f : inter;
        iou0 = inter / (tarea + pw * ph - inter);
    }
    {
        const float pcx = (x + pbx[1]) * kInv7;
        const float pcy = (y + pby[1]) * kInv7;
        const float pw = pbw[1], ph = pbh[1];
        const float tb_ = fminf(tcx + thw, pcx + pw * 0.5f) - fmaxf(tcx - thw, pcx - pw * 0.5f);
        const float lr_ = fminf(tcy + thh, pcy + ph * 0.5f) - fmaxf(tcy - thh, pcy - ph * 0.5f);
        float inter = tb_ * lr_;
        inter = (tb_ < 0.0f || lr_ < 0.0f) ? 0.0f : inter;
        iou1 = inter / (tarea + pw * ph - inter);
    }

    // argmax (first-max semantics: tie -> box 0)
    const bool b1 = (iou1 > iou0);
    const float bx = b1 ? pbx[1] : pbx[0];
    const float by = b1 ? pby[1] : pby[0];
    const float bw = b1 ? pbw[1] : pbw[0];
    const float bh = b1 ? pbh[1] : pbh[0];
    const float conf_b = b1 ? conf1 : conf0;
    const float iou_b  = b1 ? iou1  : iou0;

    const float dx = bx - tox;
    const float dy = by - toy;
    const float dw = sqrtf(bw) - sqrtf(tw);
    const float dh = sqrtf(bh) - sqrtf(th);
    const float coord = dx * dx + dy * dy + dw * dw + dh * dh;
    const float d1 = conf_b - iou_b;
    const float d2 = 1.0f - cls_t;
    const float obj   = kWC * coord + d1 * d1 + d2 * d2;
    const float noobj = kWN * (conf0 * conf0 + conf1 * conf1);

    float v = (g == 1) ? obj : noobj;

    // --- wave64 shuffle reduce, cross-wave via LDS, one atomic/block ---
    #pragma unroll
    for (int off = 32; off > 0; off >>= 1) v += __shfl_down(v, off, 64);
    if (lane == 0) wsum[wave] = v;
    __syncthreads();
    if (tid == 0) {
        atomicAdd(out, (wsum[0] + wsum[1] + wsum[2] + wsum[3]) * (1.0f / kB));
    }
}

} // namespace

extern "C" void kernel_launch(void* const* d_in, const int* in_sizes, int n_in,
                              void* d_out, int out_size, void* d_ws, size_t ws_size,
                              hipStream_t stream) {
    const float* pred = (const float*)d_in[0];
    const int*   grid = (const int*)d_in[1];
    const float* tbox = (const float*)d_in[2];
    const int*   tcls = (const int*)d_in[3];
    float* out = (float*)d_out;

    // d_out is re-poisoned (0xAA) before every timed replay -> zero it ourselves.
    zero_out<<<1, 64, 0, stream>>>(out);
    yolo_loss_kernel<<<NBLK, TPB, 0, stream>>>(pred, grid, tbox, tcls, out);
}